// Round 4
// baseline (394.075 us; speedup 1.0000x reference)
//
#include <hip/hip_runtime.h>

// LiZAttention delta-product scan, MI355X — round 6
// B=2 H=16 NC=32 CT=128 (C=64, N_ORDERS=2) D=128
// p1: norm row-sums via DPP rotate-add (VALU pipe) instead of the sqb LDS
//     round-trip (was ~3000 LDS-pipe cyc/chunk): 16-lane rg-groups are
//     aligned DPP rows; lane cl keeps rows cl, cl+16; 2 b32 partial writes
//     (rotated slots) + 128-thread reader. sqb now used only for h0 gather.
// p2: single-buffered slices (LDS 103KB -> 70KB) + uv0s handoff epilogue
//     (acc back to 2 mats, ~100 VGPR) -> 2 blocks/CU; cross-block TLP hides
//     the per-kc DMA drain and prologue/epilogue global latency.

#define Dd 128
#define NCH 32
#define YS 16777216  // ys element count; h_final follows in d_out

typedef __attribute__((ext_vector_type(4))) float floatx4;
typedef __attribute__((ext_vector_type(8))) short short8;

__device__ __forceinline__ unsigned cvtpk(float lo, float hi) {
  unsigned r;
  asm("v_cvt_pk_bf16_f32 %0, %1, %2" : "=v"(r) : "v"(lo), "v"(hi));
  return r;  // lo -> bits[15:0], hi -> bits[31:16], RNE
}

// p += rotate-within-row16(p) on the VALU pipe (DPP row_ror:N)
#define ROTADD(p, CTRL)                                              \
  p += __uint_as_float((unsigned)__builtin_amdgcn_update_dpp(        \
      0, (int)__float_as_uint(p), (CTRL), 0xF, 0xF, false))

// ---------------- Phase 1: sequential h-scan, h in registers ----------------
__global__ __launch_bounds__(512) void p1_scan(const float* __restrict__ W,
    const float* __restrict__ U, const float* __restrict__ h0,
    unsigned short* __restrict__ hws, float* __restrict__ out) {
  __shared__ float wpre[NCH * 320];      // [n][order(160)][rg(40)] padded, 40KB
  __shared__ float upre[NCH * 2 * Dd];   // [n][order][d] 32KB
  __shared__ float d10pre[NCH];
  __shared__ float sqb[Dd * 129];        // h0 gather staging only (pad 129)
  __shared__ float ppart[8 * 132];       // per-wave 16-col row partials
  __shared__ float nrm2[4 * 40];         // 2/n per row, padded [grp][40]

  const int bh = blockIdx.x;
  const int t = threadIdx.x;
  const int w = t >> 6, l = t & 63;
  const int cl = l & 15;
  const int c = (w << 4) | cl;           // column 0..127 (16 per wave)
  const int rg = l >> 4;                 // row group: rows rg*32..+31

  // ---- prefetch all W/U c=63 rows (orders 0,1) for all 32 chunks ----
  {
    const float* Wg = W + (size_t)bh * NCH * 16384;
    const float* Ug = U + (size_t)bh * NCH * 16384;
#pragma unroll
    for (int k = 0; k < 4; k++) {
      int idx4 = k * 512 + t;            // float4 idx, 2048 total
      int n = idx4 >> 6;                 // 64 f4 per chunk (2 rows of 32)
      int rem = idx4 & 63;
      int r = rem >> 5, e4 = (rem & 31) * 4;
      size_t g = (size_t)n * 16384 + (size_t)(126 + r) * Dd + e4;
      *(float4*)&upre[idx4 * 4] = *(const float4*)&Ug[g];
      *(float4*)&wpre[n * 320 + r * 160 + (e4 >> 5) * 40 + (e4 & 31)] =
          *(const float4*)&Wg[g];
    }
  }
  // ---- stage h0 (row-major) into sqb so each thread can gather its column ----
  {
    const float4* hg = (const float4*)(h0 + (size_t)bh * 16384);
#pragma unroll
    for (int k = 0; k < 8; k++) {
      int idx4 = k * 512 + t;            // 4096 total
      float4 v = hg[idx4];
      int d = idx4 >> 5, e4 = (idx4 & 31) * 4;
      sqb[d * 129 + e4 + 0] = v.x;
      sqb[d * 129 + e4 + 1] = v.y;
      sqb[d * 129 + e4 + 2] = v.z;
      sqb[d * 129 + e4 + 3] = v.w;
    }
  }
  __syncthreads();
  // ---- d10[n] = w1 . w0 for all chunks (independent of h) ----
  {
    int n = t >> 4, j = t & 15;
    const float* w0p = &wpre[n * 320 + (j >> 2) * 40 + (j & 3) * 8];
    const float* w1p = w0p + 160;
    float p = 0.f;
#pragma unroll
    for (int i = 0; i < 8; i++) p += w0p[i] * w1p[i];
    p += __shfl_xor(p, 1, 64);
    p += __shfl_xor(p, 2, 64);
    p += __shfl_xor(p, 4, 64);
    p += __shfl_xor(p, 8, 64);
    if (j == 0) d10pre[n] = p;
  }
  // ---- h column -> registers ----
  float hr[32];
#pragma unroll
  for (int i = 0; i < 32; i++) hr[i] = sqb[(rg * 32 + i) * 129 + c];
  __syncthreads();  // d10pre visible

  unsigned short* hwsb = hws + (size_t)bh * NCH * 16384;
  // ---- chunk 0 state = h0, store transposed bf16 ----
  {
    unsigned pk[16];
#pragma unroll
    for (int i = 0; i < 16; i++) pk[i] = cvtpk(hr[2 * i], hr[2 * i + 1]);
    uint4* dst = (uint4*)(hwsb + (size_t)c * Dd + rg * 32);
    dst[0] = make_uint4(pk[0], pk[1], pk[2], pk[3]);
    dst[1] = make_uint4(pk[4], pk[5], pk[6], pk[7]);
    dst[2] = make_uint4(pk[8], pk[9], pk[10], pk[11]);
    dst[3] = make_uint4(pk[12], pk[13], pk[14], pk[15]);
  }

  for (int n = 0; n < NCH; n++) {
    // conflict-free broadcast loads: rg-quads on disjoint banks (8rg+4i)
    floatx4 w0v[8], w1v[8];
    const float* wb = &wpre[n * 320 + rg * 40];
#pragma unroll
    for (int i = 0; i < 8; i++) {
      w0v[i] = *(const floatx4*)&wb[4 * i];
      w1v[i] = *(const floatx4*)&wb[160 + 4 * i];
    }
    // matvec partials over this rg's 32 rows (2 chains each for ILP)
    float a0 = 0.f, a1 = 0.f, b0 = 0.f, b1 = 0.f;
#pragma unroll
    for (int i = 0; i < 8; i += 2) {
#pragma unroll
      for (int j = 0; j < 4; j++) {
        float h0v = hr[4 * i + j];
        float h1v = hr[4 * i + 4 + j];
        a0 = fmaf(w0v[i][j], h0v, a0);
        a1 = fmaf(w1v[i][j], h0v, a1);
        b0 = fmaf(w0v[i + 1][j], h1v, b0);
        b1 = fmaf(w1v[i + 1][j], h1v, b1);
      }
    }
    a0 += b0; a1 += b1;
    // reduce across the 4 rg-lanes holding this column (same wave)
    a0 += __shfl_xor(a0, 16, 64);
    a0 += __shfl_xor(a0, 32, 64);
    a1 += __shfl_xor(a1, 16, 64);
    a1 += __shfl_xor(a1, 32, 64);
    const float u0 = upre[n * 256 + c];        // broadcast reads
    const float u1 = upre[n * 256 + Dd + c];
    const float d10 = d10pre[n];
    const float uv0 = u0 - a0;
    const float uv1 = u1 - a1 - d10 * uv0;
    // rank-2 update in registers (clamp semantics per reference)
#pragma unroll
    for (int i = 0; i < 8; i++)
#pragma unroll
      for (int j = 0; j < 4; j++) {
        int ii = 4 * i + j;
        float s = __builtin_amdgcn_fmed3f(fmaf(w0v[i][j], uv0, hr[ii]),
                                          -10000.0f, 10000.0f);
        s = __builtin_amdgcn_fmed3f(fmaf(w1v[i][j], uv1, s),
                                    -10000.0f, 10000.0f);
        hr[ii] = s;
      }
    // in-register row sums: DPP rotate-add over the 16 lanes (=16 cols) of
    // this rg-group; all lanes end with every row's 16-col partial. Lane cl
    // keeps rows cl and cl+16, writes 2 b32 partials at 13*rg-rotated slots
    // (<=3-way banks). No sqb round-trip.
    {
      float r0s = 0.f, r1s = 0.f;
#pragma unroll
      for (int i = 0; i < 32; i++) {
        float p = hr[i] * hr[i];
        ROTADD(p, 0x128);  // row_ror:8
        ROTADD(p, 0x124);  // row_ror:4
        ROTADD(p, 0x122);  // row_ror:2
        ROTADD(p, 0x121);  // row_ror:1
        if (i < 16) r0s = (cl == i) ? p : r0s;
        else        r1s = (cl == i - 16) ? p : r1s;
      }
      float* ppw = &ppart[w * 132 + rg * 32];
      ppw[(cl + 13 * rg) & 31] = r0s;
      ppw[(cl + 16 + 13 * rg) & 31] = r1s;
    }
    __syncthreads();                                   // A: partials ready
    if (t < 128) {
      int rgq = t >> 5, rr = t & 31;
      int slot = rgq * 32 + ((rr + 13 * rgq) & 31);
      float s = (ppart[slot] + ppart[132 + slot]) +
                (ppart[264 + slot] + ppart[396 + slot]) +
                (ppart[528 + slot] + ppart[660 + slot]) +
                (ppart[792 + slot] + ppart[924 + slot]);
      float nd = sqrtf(s) + 1e-6f;
      nrm2[rgq * 40 + rr] = __fdividef(2.0f, nd);
    }
    __syncthreads();                                   // B: nrm2 ready
    // gelu_norm in registers. Identity: (n/2)*x*sigmoid(a) = h*sigmoid(a),
    // x = 2h/n, a = x*(1.59576912 + 0.071354816 x^2). No n/2 rescale needed.
    floatx4 r2v[8];
    const float* nb = &nrm2[rg * 40];
#pragma unroll
    for (int i = 0; i < 8; i++) r2v[i] = *(const floatx4*)&nb[4 * i];
#pragma unroll
    for (int i = 0; i < 8; i++)
#pragma unroll
      for (int j = 0; j < 4; j++) {
        int ii = 4 * i + j;
        float h = hr[ii];
        float x = h * r2v[i][j];
        float x2 = x * x;
        float aa = x * fmaf(0.071354816f, x2, 1.59576912f);
        float ex = __expf(-aa);
        hr[ii] = __fdividef(h, 1.0f + ex);
      }
    if (n < NCH - 1) {
      unsigned pk[16];
#pragma unroll
      for (int i = 0; i < 16; i++) pk[i] = cvtpk(hr[2 * i], hr[2 * i + 1]);
      uint4* dst = (uint4*)(hwsb + (size_t)(n + 1) * 16384 + (size_t)c * Dd + rg * 32);
      dst[0] = make_uint4(pk[0], pk[1], pk[2], pk[3]);
      dst[1] = make_uint4(pk[4], pk[5], pk[6], pk[7]);
      dst[2] = make_uint4(pk[8], pk[9], pk[10], pk[11]);
      dst[3] = make_uint4(pk[12], pk[13], pk[14], pk[15]);
    } else {
      float* ob = out + YS + (size_t)bh * 16384;
#pragma unroll
      for (int i = 0; i < 32; i++) ob[(rg * 32 + i) * Dd + c] = hr[i];
    }
    // hazards: next ppart writes vs this-iter reader separated by B;
    // this-iter nrm2 reads vs next writes separated by next A.
  }
}

// ---------------- Phase 2: per-tile outputs via MFMA ----------------
// wave w (of 8): pair pr=w>>2 (0:{Q0,W0}, 1:{Q1,W1}), e-quarter eq=w&3
// 16x16x32 bf16 MFMA: A[m=lane&15][k=8*(lane>>4)+i]; B[k][n=lane&15];
//                     C/D: row=4*(lane>>4)+reg, col=lane&15   [m89/m91]
// Q/W staged per-kc slice (128 rows x 32 floats) into LDS via global_load_lds,
// XOR-swizzled: 16B chunk at phys = lin ^ ((row>>1)&7) within each row.
// Swizzle applied on the GLOBAL source (LDS dest linear, m104/m173).
// Single-buffered (70KB LDS total) -> 2 blocks/CU for cross-block TLP.

// stage one kc slice of Q and W (32KB total, 2048 x 16B chunks)
__device__ __forceinline__ void stage_slice(const float* Qb, const float* Wb,
    float* qd, float* wd, int kc, int wv6, int ln) {
#pragma unroll
  for (int i = 0; i < 4; i++) {
    int cb = i * 512 + wv6 * 64;            // uniform per wave
    int isW = cb >> 10;                     // 0: Q chunks, 1: W chunks
    int cbm = cb & 1023;                    // uniform chunk base within matrix
    int c = cbm + ln;                       // per-lane chunk
    int r = c >> 3;                         // row 0..127
    int s = (c >> 4) & 7;                   // swizzle key = (r>>1)&7
    const float* g = (isW ? Wb : Qb) + r * Dd + kc * 32 + (((c & 7) ^ s) << 2);
    float* l = (isW ? wd : qd) + (cbm << 2);  // wave-uniform; HW adds lane*16
    __builtin_amdgcn_global_load_lds(
        (const __attribute__((address_space(1))) void*)g,
        (__attribute__((address_space(3))) void*)l, 16, 0, 0);
  }
}

__global__ __launch_bounds__(512, 4) void p2_out(const float* __restrict__ Q,
    const float* __restrict__ W, const float* __restrict__ U,
    const unsigned short* __restrict__ hws, float* __restrict__ out) {
  __shared__ unsigned short hT[Dd * 136];  // transposed h, pad 136 (34816 B)
  __shared__ float qsl[4096];              // Q kc-slice, swizzled (16KB)
  __shared__ float wsl[4096];              // W kc-slice, swizzled (16KB)
  __shared__ float d10s[64], dq1s[64];
  __shared__ float dps[512];

  const int bid = blockIdx.x;
  const int n = bid & 31, bh = bid >> 5;
  const size_t base = (size_t)(bh * NCH + n) * 16384;
  const float* Qb = Q + base;
  const float* Wb = W + base;
  const float* Ub = U + base;
  float* Ob = out + base;
  const int t = threadIdx.x;
  const int wv6 = t >> 6, ln = t & 63;

  // issue async DMA for kc=0 slice first; it lands during the prologue
  stage_slice(Qb, Wb, &qsl[0], &wsl[0], 0, wv6, ln);

  // stage hT (global e-major, stride 128) -> LDS stride 136
  {
    const uint4* src = (const uint4*)(hws + base);
#pragma unroll
    for (int i = 0; i < 4; i++) {
      int idx = t + i * 512;               // uint4 idx, 2048 total
      uint4 v = src[idx];
      int e = idx >> 4, j = idx & 15;
      *(uint4*)&hT[e * 136 + j * 8] = v;
    }
  }
  // per-c dots: d10[c]=w1.w0, dq1[c]=q1.w0  (fp32 from global, float4 loads)
  {
    int which = t >> 8, tt = t & 255;
    int cc = tt >> 2, part = tt & 3;
    const float4* ar = (const float4*)((which ? Qb : Wb) + (2 * cc + 1) * Dd + part * 32);
    const float4* w0r = (const float4*)(Wb + (2 * cc) * Dd + part * 32);
    float s = 0.f;
#pragma unroll
    for (int i = 0; i < 8; i++) {
      float4 a = ar[i], b = w0r[i];
      s += a.x * b.x + a.y * b.y + a.z * b.z + a.w * b.w;
    }
    dps[which * 256 + tt] = s;
  }
  __syncthreads();  // drains vmcnt(0)+lgkm: slice0 DMA, hT, dps all ready
  if (t < 128) {
    int which = t >> 6, cc = t & 63;
    const float* p = dps + which * 256 + cc * 4;
    float s = p[0] + p[1] + p[2] + p[3];
    (which ? dq1s : d10s)[cc] = s;        // read in epilogue; >=4 barriers away
  }

  const int pr = wv6 >> 2, eq = wv6 & 3;
  const int lm = ln & 15, lq = ln >> 4;
  const int sw = lm & 7;                   // swizzle key ((r>>1)&7 = lm&7)
  const int i0 = ((2 * lq) ^ sw) << 2;     // phys float offset of f0 chunk
  const int i1 = ((2 * lq + 1) ^ sw) << 2; // phys float offset of f1 chunk

  floatx4 acc[2][4][2];  // [mat 0=Q_pr,1=W_pr][ctile][etile]
#pragma unroll
  for (int m = 0; m < 2; m++)
#pragma unroll
    for (int ci = 0; ci < 4; ci++)
#pragma unroll
      for (int j = 0; j < 2; j++) acc[m][ci][j] = (floatx4){0.f, 0.f, 0.f, 0.f};

  for (int kc = 0; kc < 4; kc++) {
    const int k0 = kc * 32;
    short8 bfr[2];
#pragma unroll
    for (int j = 0; j < 2; j++) {
      int ee = (2 * eq + j) * 16 + lm;
      bfr[j] = *(const short8*)&hT[ee * 136 + k0 + 8 * lq];  // ds_read_b128
    }
#pragma unroll
    for (int ci = 0; ci < 4; ci++) {
      const int rb = (32 * ci + 2 * lm) * 32 + pr * 32;  // this pair's row base
      {  // m0: Q_pr
        const float* p = &qsl[rb];
        floatx4 g0 = *(const floatx4*)(p + i0);
        floatx4 g1 = *(const floatx4*)(p + i1);
        union { short8 v; unsigned u[4]; } af;
        af.u[0] = cvtpk(g0[0], g0[1]);
        af.u[1] = cvtpk(g0[2], g0[3]);
        af.u[2] = cvtpk(g1[0], g1[1]);
        af.u[3] = cvtpk(g1[2], g1[3]);
        acc[0][ci][0] = __builtin_amdgcn_mfma_f32_16x16x32_bf16(af.v, bfr[0], acc[0][ci][0], 0, 0, 0);
        acc[0][ci][1] = __builtin_amdgcn_mfma_f32_16x16x32_bf16(af.v, bfr[1], acc[0][ci][1], 0, 0, 0);
      }
      {  // m1: W_pr
        const float* p = &wsl[rb];
        floatx4 g0 = *(const floatx4*)(p + i0);
        floatx4 g1 = *(const floatx4*)(p + i1);
        union { short8 v; unsigned u[4]; } af;
        af.u[0] = cvtpk(g0[0], g0[1]);
        af.u[1] = cvtpk(g0[2], g0[3]);
        af.u[2] = cvtpk(g1[0], g1[1]);
        af.u[3] = cvtpk(g1[2], g1[3]);
        acc[1][ci][0] = __builtin_amdgcn_mfma_f32_16x16x32_bf16(af.v, bfr[0], acc[1][ci][0], 0, 0, 0);
        acc[1][ci][1] = __builtin_amdgcn_mfma_f32_16x16x32_bf16(af.v, bfr[1], acc[1][ci][1], 0, 0, 0);
      }
    }
    __syncthreads();  // all reads of this slice done
    if (kc < 3) {
      stage_slice(Qb, Wb, &qsl[0], &wsl[0], kc + 1, wv6, ln);
      __syncthreads();  // vmcnt(0) drain: next slice landed
    }
  }

  // hT dead after kc loop -> alias as uv0 (fp32 64x128 = 32KB <= 34816B)
  float* uv0s = (float*)hT;
  if (pr == 0) {
#pragma unroll
    for (int ci = 0; ci < 4; ci++)
#pragma unroll
      for (int j = 0; j < 2; j++) {
        int ee = (2 * eq + j) * 16 + lm;
#pragma unroll
        for (int r = 0; r < 4; r++) {
          int cc = ci * 16 + lq * 4 + r;
          float T0 = acc[1][ci][j][r];   // w0^T h
          float Q0h = acc[0][ci][j][r];  // q0^T h
          float u0 = Ub[(2 * cc) * Dd + ee];
          float q0 = Qb[(2 * cc) * Dd + ee];
          float uv0 = u0 - T0;
          uv0s[cc * Dd + ee] = uv0;
          Ob[(2 * cc) * Dd + ee] = q0 * uv0 + Q0h;
        }
      }
  }
  __syncthreads();
  if (pr == 1) {
#pragma unroll
    for (int ci = 0; ci < 4; ci++)
#pragma unroll
      for (int j = 0; j < 2; j++) {
        int ee = (2 * eq + j) * 16 + lm;
#pragma unroll
        for (int r = 0; r < 4; r++) {
          int cc = ci * 16 + lq * 4 + r;
          float T1 = acc[1][ci][j][r];   // w1^T h
          float Q1h = acc[0][ci][j][r];  // q1^T h
          float u1 = Ub[(2 * cc + 1) * Dd + ee];
          float q1 = Qb[(2 * cc + 1) * Dd + ee];
          float uv0 = uv0s[cc * Dd + ee];
          float uv1 = u1 - T1 - d10s[cc] * uv0;
          Ob[(2 * cc + 1) * Dd + ee] = q1 * uv1 + Q1h + dq1s[cc] * uv0;
        }
      }
  }
}

extern "C" void kernel_launch(void* const* d_in, const int* in_sizes, int n_in,
                              void* d_out, int out_size, void* d_ws, size_t ws_size,
                              hipStream_t stream) {
  const float* Q = (const float*)d_in[0];
  const float* W = (const float*)d_in[1];
  const float* U = (const float*)d_in[2];
  const float* h0 = (const float*)d_in[3];
  float* out = (float*)d_out;
  unsigned short* hws = (unsigned short*)d_ws;  // 32*32*16384 bf16 = 32 MiB, transposed [e][d]

  p1_scan<<<32, 512, 0, stream>>>(W, U, h0, hws, out);
  p2_out<<<1024, 512, 0, stream>>>(Q, W, U, hws, out);
}

// Round 5
// 375.691 us; speedup vs baseline: 1.0489x; 1.0489x over previous
//
#include <hip/hip_runtime.h>

// LiZAttention delta-product scan, MI355X — round 7
// B=2 H=16 NC=32 CT=128 (C=64, N_ORDERS=2) D=128
// p1: 1024 threads (16 waves, 4/SIMD) for latency hiding — wave = 8 cols x
//     8 row-groups of 16 rows. Matvec reduce = shfl_xor(8,16,32). Norm via
//     sqb LDS round-trip (round-4 structure, NOT DPP — that regressed):
//     - wpre/nrm2 stride-20 pads: 20*rg mod 32 hits all 8 bank-quads
//     - sqb writes rotated (c+20rg)&31 -> exactly 2-way (free)
//     - sumsq reads: 4-blocks rotated (b+sst)&3 -> exactly 2-way
// p2: unchanged from round 6 (single-buffered slices, 2 blocks/CU).

#define Dd 128
#define NCH 32
#define YS 16777216  // ys element count; h_final follows in d_out

typedef __attribute__((ext_vector_type(4))) float floatx4;
typedef __attribute__((ext_vector_type(8))) short short8;

__device__ __forceinline__ unsigned cvtpk(float lo, float hi) {
  unsigned r;
  asm("v_cvt_pk_bf16_f32 %0, %1, %2" : "=v"(r) : "v"(lo), "v"(hi));
  return r;  // lo -> bits[15:0], hi -> bits[31:16], RNE
}

// ---------------- Phase 1: sequential h-scan, h in registers ----------------
__global__ __launch_bounds__(1024, 4) void p1_scan(const float* __restrict__ W,
    const float* __restrict__ U, const float* __restrict__ h0,
    unsigned short* __restrict__ hws, float* __restrict__ out) {
  __shared__ float wpre[NCH * 320];      // [n][order(160)][rg(20)] padded, 40KB
  __shared__ float upre[NCH * 2 * Dd];   // [n][order][d] 32KB
  __shared__ float d10pre[NCH];
  __shared__ float sqb[Dd * 129];        // h' staging for norm (pad 129)
  __shared__ float nrm2[8 * 20];         // 2/n per row, padded [grp][20]

  const int bh = blockIdx.x;
  const int t = threadIdx.x;             // 0..1023
  const int w = t >> 6, l = t & 63;
  const int cl = l & 7;
  const int c = (w << 3) | cl;           // column 0..127 (8 per wave)
  const int rg = l >> 3;                 // row group: rows rg*16..+15

  // ---- prefetch all W/U c=63 rows (orders 0,1) for all 32 chunks ----
  {
    const float* Wg = W + (size_t)bh * NCH * 16384;
    const float* Ug = U + (size_t)bh * NCH * 16384;
#pragma unroll
    for (int k = 0; k < 2; k++) {
      int idx4 = k * 1024 + t;           // float4 idx, 2048 total
      int n = idx4 >> 6;                 // 64 f4 per chunk (2 rows of 32)
      int rem = idx4 & 63;
      int r = rem >> 5, e4 = (rem & 31) * 4;
      size_t g = (size_t)n * 16384 + (size_t)(126 + r) * Dd + e4;
      *(float4*)&upre[idx4 * 4] = *(const float4*)&Ug[g];
      *(float4*)&wpre[n * 320 + r * 160 + (e4 >> 4) * 20 + (e4 & 15)] =
          *(const float4*)&Wg[g];
    }
  }
  // ---- stage h0 (row-major) into sqb so each thread can gather its column ----
  {
    const float4* hg = (const float4*)(h0 + (size_t)bh * 16384);
#pragma unroll
    for (int k = 0; k < 4; k++) {
      int idx4 = k * 1024 + t;           // 4096 total
      float4 v = hg[idx4];
      int d = idx4 >> 5, e4 = (idx4 & 31) * 4;
      sqb[d * 129 + e4 + 0] = v.x;
      sqb[d * 129 + e4 + 1] = v.y;
      sqb[d * 129 + e4 + 2] = v.z;
      sqb[d * 129 + e4 + 3] = v.w;
    }
  }
  __syncthreads();
  // ---- d10[n] = w1 . w0 for all chunks (independent of h) ----
  {
    int n = t >> 5, j = t & 31;          // 32 threads per chunk, 4 floats each
    const float* w0p = &wpre[n * 320 + (j >> 2) * 20 + (j & 3) * 4];
    const float* w1p = w0p + 160;
    float p = 0.f;
#pragma unroll
    for (int i = 0; i < 4; i++) p += w0p[i] * w1p[i];
    p += __shfl_xor(p, 1, 64);
    p += __shfl_xor(p, 2, 64);
    p += __shfl_xor(p, 4, 64);
    p += __shfl_xor(p, 8, 64);
    p += __shfl_xor(p, 16, 64);
    if (j == 0) d10pre[n] = p;
  }
  // ---- h column -> registers ----
  float hr[16];
#pragma unroll
  for (int i = 0; i < 16; i++) hr[i] = sqb[(rg * 16 + i) * 129 + c];
  __syncthreads();  // d10pre visible; sqb free for reuse

  // rotated column slot: bank(write) = (16rg + (c+20rg)&31 + i) mod 32
  //                                  = (4rg + c + i) mod 32 -> exactly 2-way.
  const int cpos = (c & 96) | ((c + 20 * rg) & 31);
  float* sqw = &sqb[rg * 16 * 129 + cpos];             // + i*129 per row
  const int srow = t >> 3, sst = t & 7;                // sumsq: row, stripe
  const float* sqr = &sqb[srow * 129 + sst * 16];

  unsigned short* hwsb = hws + (size_t)bh * NCH * 16384;
  // ---- chunk 0 state = h0, store transposed bf16 ----
  {
    unsigned pk[8];
#pragma unroll
    for (int i = 0; i < 8; i++) pk[i] = cvtpk(hr[2 * i], hr[2 * i + 1]);
    uint4* dst = (uint4*)(hwsb + (size_t)c * Dd + rg * 16);
    dst[0] = make_uint4(pk[0], pk[1], pk[2], pk[3]);
    dst[1] = make_uint4(pk[4], pk[5], pk[6], pk[7]);
  }

  for (int n = 0; n < NCH; n++) {
    // conflict-free broadcast loads: 8 rg-quads on disjoint bank-quads (20rg)
    floatx4 w0v[4], w1v[4];
    const float* wb = &wpre[n * 320 + rg * 20];
#pragma unroll
    for (int i = 0; i < 4; i++) {
      w0v[i] = *(const floatx4*)&wb[4 * i];
      w1v[i] = *(const floatx4*)&wb[160 + 4 * i];
    }
    // matvec partials over this rg's 16 rows (2 chains each for ILP)
    float a0 = 0.f, a1 = 0.f, b0 = 0.f, b1 = 0.f;
#pragma unroll
    for (int i = 0; i < 4; i += 2) {
#pragma unroll
      for (int j = 0; j < 4; j++) {
        float h0v = hr[4 * i + j];
        float h1v = hr[4 * i + 4 + j];
        a0 = fmaf(w0v[i][j], h0v, a0);
        a1 = fmaf(w1v[i][j], h0v, a1);
        b0 = fmaf(w0v[i + 1][j], h1v, b0);
        b1 = fmaf(w1v[i + 1][j], h1v, b1);
      }
    }
    a0 += b0; a1 += b1;
    // reduce across the 8 rg-lanes holding this column (same wave)
    a0 += __shfl_xor(a0, 8, 64);
    a0 += __shfl_xor(a0, 16, 64);
    a0 += __shfl_xor(a0, 32, 64);
    a1 += __shfl_xor(a1, 8, 64);
    a1 += __shfl_xor(a1, 16, 64);
    a1 += __shfl_xor(a1, 32, 64);
    const float u0 = upre[n * 256 + c];        // broadcast reads
    const float u1 = upre[n * 256 + Dd + c];
    const float d10 = d10pre[n];
    const float uv0 = u0 - a0;
    const float uv1 = u1 - a1 - d10 * uv0;
    // rank-2 update in registers; write h' to sqb for row-norm
#pragma unroll
    for (int i = 0; i < 4; i++)
#pragma unroll
      for (int j = 0; j < 4; j++) {
        int ii = 4 * i + j;
        float s = __builtin_amdgcn_fmed3f(fmaf(w0v[i][j], uv0, hr[ii]),
                                          -10000.0f, 10000.0f);
        s = __builtin_amdgcn_fmed3f(fmaf(w1v[i][j], uv1, s),
                                    -10000.0f, 10000.0f);
        hr[ii] = s;
        sqw[ii * 129] = s;
      }
    __syncthreads();                                   // A: sqb ready
    // row sum-of-squares: thread = (row srow, stripe sst of 16 cols); read in
    // 4 blocks of 4, block order rotated by sst -> banks
    // (srow + 16sst + 4((b+sst)&3) + i) are exactly 2-way = free. Row sum is
    // permutation-invariant so the cpos column shuffle doesn't matter.
    {
      float acc = 0.f, acc2 = 0.f;
#pragma unroll
      for (int b = 0; b < 4; b++) {
        const float* p = sqr + 4 * ((b + sst) & 3);
        float v0 = p[0], v1 = p[1], v2 = p[2], v3 = p[3];
        acc = fmaf(v0, v0, acc);
        acc2 = fmaf(v1, v1, acc2);
        acc = fmaf(v2, v2, acc);
        acc2 = fmaf(v3, v3, acc2);
      }
      acc += acc2;
      acc += __shfl_xor(acc, 1, 64);
      acc += __shfl_xor(acc, 2, 64);
      acc += __shfl_xor(acc, 4, 64);
      if (sst == 0) {
        float nd = sqrtf(acc) + 1e-6f;
        nrm2[(srow >> 4) * 20 + (srow & 15)] = __fdividef(2.0f, nd);
      }
    }
    __syncthreads();                                   // B: nrm2 ready
    // gelu_norm in registers. Identity: (n/2)*x*sigmoid(a) = h*sigmoid(a),
    // x = 2h/n, a = x*(1.59576912 + 0.071354816 x^2). No n/2 rescale needed.
    floatx4 r2v[4];
    const float* nb = &nrm2[rg * 20];
#pragma unroll
    for (int i = 0; i < 4; i++) r2v[i] = *(const floatx4*)&nb[4 * i];
#pragma unroll
    for (int i = 0; i < 4; i++)
#pragma unroll
      for (int j = 0; j < 4; j++) {
        int ii = 4 * i + j;
        float h = hr[ii];
        float x = h * r2v[i][j];
        float x2 = x * x;
        float aa = x * fmaf(0.071354816f, x2, 1.59576912f);
        float ex = __expf(-aa);
        hr[ii] = __fdividef(h, 1.0f + ex);
      }
    if (n < NCH - 1) {
      unsigned pk[8];
#pragma unroll
      for (int i = 0; i < 8; i++) pk[i] = cvtpk(hr[2 * i], hr[2 * i + 1]);
      uint4* dst = (uint4*)(hwsb + (size_t)(n + 1) * 16384 + (size_t)c * Dd + rg * 16);
      dst[0] = make_uint4(pk[0], pk[1], pk[2], pk[3]);
      dst[1] = make_uint4(pk[4], pk[5], pk[6], pk[7]);
    } else {
      float* ob = out + YS + (size_t)bh * 16384;
#pragma unroll
      for (int i = 0; i < 16; i++) ob[(rg * 16 + i) * Dd + c] = hr[i];
    }
    // hazards: next-iter sqb writes vs this-iter sqb reads separated by B;
    // this-iter nrm2 reads vs next-iter nrm2 writes separated by next A.
  }
}

// ---------------- Phase 2: per-tile outputs via MFMA ----------------
// wave w (of 8): pair pr=w>>2 (0:{Q0,W0}, 1:{Q1,W1}), e-quarter eq=w&3
// 16x16x32 bf16 MFMA: A[m=lane&15][k=8*(lane>>4)+i]; B[k][n=lane&15];
//                     C/D: row=4*(lane>>4)+reg, col=lane&15   [m89/m91]
// Q/W staged per-kc slice (128 rows x 32 floats) into LDS via global_load_lds,
// XOR-swizzled: 16B chunk at phys = lin ^ ((row>>1)&7) within each row.
// Swizzle applied on the GLOBAL source (LDS dest linear, m104/m173).
// Single-buffered (70KB LDS total) -> 2 blocks/CU for cross-block TLP.

// stage one kc slice of Q and W (32KB total, 2048 x 16B chunks)
__device__ __forceinline__ void stage_slice(const float* Qb, const float* Wb,
    float* qd, float* wd, int kc, int wv6, int ln) {
#pragma unroll
  for (int i = 0; i < 4; i++) {
    int cb = i * 512 + wv6 * 64;            // uniform per wave
    int isW = cb >> 10;                     // 0: Q chunks, 1: W chunks
    int cbm = cb & 1023;                    // uniform chunk base within matrix
    int c = cbm + ln;                       // per-lane chunk
    int r = c >> 3;                         // row 0..127
    int s = (c >> 4) & 7;                   // swizzle key = (r>>1)&7
    const float* g = (isW ? Wb : Qb) + r * Dd + kc * 32 + (((c & 7) ^ s) << 2);
    float* l = (isW ? wd : qd) + (cbm << 2);  // wave-uniform; HW adds lane*16
    __builtin_amdgcn_global_load_lds(
        (const __attribute__((address_space(1))) void*)g,
        (__attribute__((address_space(3))) void*)l, 16, 0, 0);
  }
}

__global__ __launch_bounds__(512, 4) void p2_out(const float* __restrict__ Q,
    const float* __restrict__ W, const float* __restrict__ U,
    const unsigned short* __restrict__ hws, float* __restrict__ out) {
  __shared__ unsigned short hT[Dd * 136];  // transposed h, pad 136 (34816 B)
  __shared__ float qsl[4096];              // Q kc-slice, swizzled (16KB)
  __shared__ float wsl[4096];              // W kc-slice, swizzled (16KB)
  __shared__ float d10s[64], dq1s[64];
  __shared__ float dps[512];

  const int bid = blockIdx.x;
  const int n = bid & 31, bh = bid >> 5;
  const size_t base = (size_t)(bh * NCH + n) * 16384;
  const float* Qb = Q + base;
  const float* Wb = W + base;
  const float* Ub = U + base;
  float* Ob = out + base;
  const int t = threadIdx.x;
  const int wv6 = t >> 6, ln = t & 63;

  // issue async DMA for kc=0 slice first; it lands during the prologue
  stage_slice(Qb, Wb, &qsl[0], &wsl[0], 0, wv6, ln);

  // stage hT (global e-major, stride 128) -> LDS stride 136
  {
    const uint4* src = (const uint4*)(hws + base);
#pragma unroll
    for (int i = 0; i < 4; i++) {
      int idx = t + i * 512;               // uint4 idx, 2048 total
      uint4 v = src[idx];
      int e = idx >> 4, j = idx & 15;
      *(uint4*)&hT[e * 136 + j * 8] = v;
    }
  }
  // per-c dots: d10[c]=w1.w0, dq1[c]=q1.w0  (fp32 from global, float4 loads)
  {
    int which = t >> 8, tt = t & 255;
    int cc = tt >> 2, part = tt & 3;
    const float4* ar = (const float4*)((which ? Qb : Wb) + (2 * cc + 1) * Dd + part * 32);
    const float4* w0r = (const float4*)(Wb + (2 * cc) * Dd + part * 32);
    float s = 0.f;
#pragma unroll
    for (int i = 0; i < 8; i++) {
      float4 a = ar[i], b = w0r[i];
      s += a.x * b.x + a.y * b.y + a.z * b.z + a.w * b.w;
    }
    dps[which * 256 + tt] = s;
  }
  __syncthreads();  // drains vmcnt(0)+lgkm: slice0 DMA, hT, dps all ready
  if (t < 128) {
    int which = t >> 6, cc = t & 63;
    const float* p = dps + which * 256 + cc * 4;
    float s = p[0] + p[1] + p[2] + p[3];
    (which ? dq1s : d10s)[cc] = s;        // read in epilogue; >=4 barriers away
  }

  const int pr = wv6 >> 2, eq = wv6 & 3;
  const int lm = ln & 15, lq = ln >> 4;
  const int sw = lm & 7;                   // swizzle key ((r>>1)&7 = lm&7)
  const int i0 = ((2 * lq) ^ sw) << 2;     // phys float offset of f0 chunk
  const int i1 = ((2 * lq + 1) ^ sw) << 2; // phys float offset of f1 chunk

  floatx4 acc[2][4][2];  // [mat 0=Q_pr,1=W_pr][ctile][etile]
#pragma unroll
  for (int m = 0; m < 2; m++)
#pragma unroll
    for (int ci = 0; ci < 4; ci++)
#pragma unroll
      for (int j = 0; j < 2; j++) acc[m][ci][j] = (floatx4){0.f, 0.f, 0.f, 0.f};

  for (int kc = 0; kc < 4; kc++) {
    const int k0 = kc * 32;
    short8 bfr[2];
#pragma unroll
    for (int j = 0; j < 2; j++) {
      int ee = (2 * eq + j) * 16 + lm;
      bfr[j] = *(const short8*)&hT[ee * 136 + k0 + 8 * lq];  // ds_read_b128
    }
#pragma unroll
    for (int ci = 0; ci < 4; ci++) {
      const int rb = (32 * ci + 2 * lm) * 32 + pr * 32;  // this pair's row base
      {  // m0: Q_pr
        const float* p = &qsl[rb];
        floatx4 g0 = *(const floatx4*)(p + i0);
        floatx4 g1 = *(const floatx4*)(p + i1);
        union { short8 v; unsigned u[4]; } af;
        af.u[0] = cvtpk(g0[0], g0[1]);
        af.u[1] = cvtpk(g0[2], g0[3]);
        af.u[2] = cvtpk(g1[0], g1[1]);
        af.u[3] = cvtpk(g1[2], g1[3]);
        acc[0][ci][0] = __builtin_amdgcn_mfma_f32_16x16x32_bf16(af.v, bfr[0], acc[0][ci][0], 0, 0, 0);
        acc[0][ci][1] = __builtin_amdgcn_mfma_f32_16x16x32_bf16(af.v, bfr[1], acc[0][ci][1], 0, 0, 0);
      }
      {  // m1: W_pr
        const float* p = &wsl[rb];
        floatx4 g0 = *(const floatx4*)(p + i0);
        floatx4 g1 = *(const floatx4*)(p + i1);
        union { short8 v; unsigned u[4]; } af;
        af.u[0] = cvtpk(g0[0], g0[1]);
        af.u[1] = cvtpk(g0[2], g0[3]);
        af.u[2] = cvtpk(g1[0], g1[1]);
        af.u[3] = cvtpk(g1[2], g1[3]);
        acc[1][ci][0] = __builtin_amdgcn_mfma_f32_16x16x32_bf16(af.v, bfr[0], acc[1][ci][0], 0, 0, 0);
        acc[1][ci][1] = __builtin_amdgcn_mfma_f32_16x16x32_bf16(af.v, bfr[1], acc[1][ci][1], 0, 0, 0);
      }
    }
    __syncthreads();  // all reads of this slice done
    if (kc < 3) {
      stage_slice(Qb, Wb, &qsl[0], &wsl[0], kc + 1, wv6, ln);
      __syncthreads();  // vmcnt(0) drain: next slice landed
    }
  }

  // hT dead after kc loop -> alias as uv0 (fp32 64x128 = 32KB <= 34816B)
  float* uv0s = (float*)hT;
  if (pr == 0) {
#pragma unroll
    for (int ci = 0; ci < 4; ci++)
#pragma unroll
      for (int j = 0; j < 2; j++) {
        int ee = (2 * eq + j) * 16 + lm;
#pragma unroll
        for (int r = 0; r < 4; r++) {
          int cc = ci * 16 + lq * 4 + r;
          float T0 = acc[1][ci][j][r];   // w0^T h
          float Q0h = acc[0][ci][j][r];  // q0^T h
          float u0 = Ub[(2 * cc) * Dd + ee];
          float q0 = Qb[(2 * cc) * Dd + ee];
          float uv0 = u0 - T0;
          uv0s[cc * Dd + ee] = uv0;
          Ob[(2 * cc) * Dd + ee] = q0 * uv0 + Q0h;
        }
      }
  }
  __syncthreads();
  if (pr == 1) {
#pragma unroll
    for (int ci = 0; ci < 4; ci++)
#pragma unroll
      for (int j = 0; j < 2; j++) {
        int ee = (2 * eq + j) * 16 + lm;
#pragma unroll
        for (int r = 0; r < 4; r++) {
          int cc = ci * 16 + lq * 4 + r;
          float T1 = acc[1][ci][j][r];   // w1^T h
          float Q1h = acc[0][ci][j][r];  // q1^T h
          float u1 = Ub[(2 * cc + 1) * Dd + ee];
          float q1 = Qb[(2 * cc + 1) * Dd + ee];
          float uv0 = uv0s[cc * Dd + ee];
          float uv1 = u1 - T1 - d10s[cc] * uv0;
          Ob[(2 * cc + 1) * Dd + ee] = q1 * uv1 + Q1h + dq1s[cc] * uv0;
        }
      }
  }
}

extern "C" void kernel_launch(void* const* d_in, const int* in_sizes, int n_in,
                              void* d_out, int out_size, void* d_ws, size_t ws_size,
                              hipStream_t stream) {
  const float* Q = (const float*)d_in[0];
  const float* W = (const float*)d_in[1];
  const float* U = (const float*)d_in[2];
  const float* h0 = (const float*)d_in[3];
  float* out = (float*)d_out;
  unsigned short* hws = (unsigned short*)d_ws;  // 32*32*16384 bf16 = 32 MiB, transposed [e][d]

  p1_scan<<<32, 1024, 0, stream>>>(W, U, h0, hws, out);
  p2_out<<<1024, 512, 0, stream>>>(Q, W, U, hws, out);
}